// Round 1
// 1344.436 us; speedup vs baseline: 1.4492x; 1.4492x over previous
//
#include <hip/hip_runtime.h>

// ---------------------------------------------------------------------------
// 2-layer LSTM (H=51) + Linear(51,1), B=1024, T=1024, fp32.
// R15 = R14 restructured for 2 waves/SIMD + split-plane LDS h:
//   Theory: R14 was latency-serialization-bound at 1 wave/SIMD (occ 2.65%,
//   MfmaUtil 5.3%, VALUBusy 13%): ~2000 of 4430 cyc/step were unoverlapped
//   stalls (ds_read latency, exp/rcp latency, MFMA chains, 2.2e7 LDS bank
//   conflict cycles).
//   - 512 thr = 8 waves, 2/SIMD (waves_per_eu(2,2)): wave w owns tiles
//     {w, 8+w} (t>=13 dummy). Per-wave weight regs halve (96) -> VGPR<=256.
//     SIMD slot load 4/3/3/3 as before, but 2-way TLP hides latency.
//   - h stored PRE-SPLIT: planes [buf][{h1hi,h1lo,h2hi,h2lo}][mcol][k] bf16,
//     row stride 88 (176B): B-frag build = 8x ds_read_b128, ZERO v_perm
//     (was 32x ds_read_b32 + 32x v_perm). Start banks 12m mod 32 per 8-lane
//     group = conflict-free permutation. Producer writes 2x ds_write_b16
//     per h (same RNE hi/lo values as R14's pack_hl -> numerics identical).
//   - gates = Whi.hhi + Whi.hlo + Wlo.hhi (3 mfma terms, R14-proven).
//   - W rows permuted prow=4u+g -> lane-local c/h update (R9+ proven).
//   - ONE barrier/step, L2 one step behind L1, ping-pong buffers, deferred
//     y(k-2) on wave 7 (reads hi+lo planes, == R14's unpack_f), k==0 guard.
// ---------------------------------------------------------------------------

#define H     51
#define NROW  204      // 4*H
#define TLEN  1024
#define BPB   16       // batches per block (= mfma N)
#define NTHR  512      // 8 waves
#define NBLK  64
#define KPAD  88       // bf16 row stride (176B) -> conflict-free b128 reads

typedef __attribute__((ext_vector_type(8))) short bf16x8;   // 8 bf16 = 4 VGPRs
typedef __attribute__((ext_vector_type(4))) float f4;

__device__ __forceinline__ float frcp(float x) { return __builtin_amdgcn_rcpf(x); }
__device__ __forceinline__ float sigm(float x) { return frcp(1.0f + __expf(-x)); }
__device__ __forceinline__ float tanh_(float x) {
    return 1.0f - 2.0f * frcp(__expf(2.0f * x) + 1.0f);
}

__device__ __forceinline__ short bf_rne(float f) {        // fp32 -> bf16 RNE
    unsigned u = __float_as_uint(f);
    return (short)((u + 0x7FFFu + ((u >> 16) & 1u)) >> 16);
}
__device__ __forceinline__ float bf_f(short h) {          // bf16 -> fp32
    return __uint_as_float(((unsigned)(unsigned short)h) << 16);
}

__device__ __forceinline__ bf16x8 lds16(const short* p) { // one ds_read_b128
    return *(const bf16x8*)__builtin_assume_aligned(p, 16);
}

#define MFMA(ACC, A, B) \
    ACC = __builtin_amdgcn_mfma_f32_16x16x32_bf16((A), (B), (ACC), 0, 0, 0)

// A-frag for 16x16x32: lane holds A[m=lane&15][k=quad*8+j], j=0..7.
// Source W is [204][51] row-major, PyTorch rows g*51+u; permuted row
// prow = 4u+g -> src row = (prow&3)*51 + (prow>>2). Zero-pad prow>=204, k>=51.
__device__ __forceinline__ void load_wfrag(const float* __restrict__ W,
                                           int tile, int kt, int q, int mcol,
                                           bf16x8* hi, bf16x8* lo)
{
    bf16x8 h, l;
    const int prow = tile * 16 + mcol;
#pragma unroll
    for (int j = 0; j < 8; ++j) {
        const int kk = kt * 32 + q * 8 + j;
        float v = 0.0f;
        if (prow < NROW && kk < H) {
            const int srow = (prow & 3) * H + (prow >> 2);
            v = W[srow * H + kk];
        }
        const short hb = bf_rne(v);
        h[j] = hb;
        l[j] = bf_rne(v - bf_f(hb));
    }
    *hi = h;
    *lo = l;
}

__global__
__attribute__((amdgpu_flat_work_group_size(NTHR, NTHR), amdgpu_waves_per_eu(2, 2)))
void lstm2_kernel(const float* __restrict__ input,
                  const float* __restrict__ W_ih1, const float* __restrict__ W_hh1,
                  const float* __restrict__ b_ih1, const float* __restrict__ b_hh1,
                  const float* __restrict__ W_ih2, const float* __restrict__ W_hh2,
                  const float* __restrict__ b_ih2, const float* __restrict__ b_hh2,
                  const float* __restrict__ W_lin, const float* __restrict__ b_lin,
                  float* __restrict__ out)
{
    const int tid  = threadIdx.x;
    const int w    = tid >> 6;        // wave 0..7
    const int lane = tid & 63;
    const int q    = lane >> 4;       // quad
    const int mcol = lane & 15;       // batch column (and A-frag m)
    const int b0   = blockIdx.x * BPB;

    // [buf][plane][mcol][k]; planes: 0=h1hi 1=h1lo 2=h2hi 3=h2lo.
    // Rows k in [51,88) stay zero (init below, never written).
    __shared__ __align__(16) short hb[2][4][BPB][KPAD];

    {
        short* hz = &hb[0][0][0][0];
        for (int i = tid; i < 2 * 4 * BPB * KPAD; i += NTHR) hz[i] = 0;
    }

    // ---- persistent weight fragments: wave w owns tiles {w, 8+w} ----------
    bf16x8 A1h[2][2], A1l[2][2];          // W_hh1 hi/lo  x Ktile
    bf16x8 Aih[2][2], Ail[2][2];          // W_ih2 hi/lo
    bf16x8 Ahh[2][2], Ahl[2][2];          // W_hh2 hi/lo
    f4 bb1[2], bb2[2], wxv[2];
    float c1[2], c2[2];
    int tiles[2];
    tiles[0] = w;                          // 0..7
    tiles[1] = 8 + w;                      // 8..15 (>=13 -> dummy)
#pragma unroll
    for (int s = 0; s < 2; ++s) {
        const int t = tiles[s];
        const int u = 4 * t + q;          // this lane's unit for slot s
        c1[s] = 0.0f; c2[s] = 0.0f;
#pragma unroll
        for (int kt = 0; kt < 2; ++kt) {
            load_wfrag(W_hh1, t, kt, q, mcol, &A1h[s][kt], &A1l[s][kt]);
            load_wfrag(W_ih2, t, kt, q, mcol, &Aih[s][kt], &Ail[s][kt]);
            load_wfrag(W_hh2, t, kt, q, mcol, &Ahh[s][kt], &Ahl[s][kt]);
        }
#pragma unroll
        for (int j = 0; j < 4; ++j) {     // gate j of unit u (PyTorch row j*H+u)
            const bool v = (t < 13) && (u < H);
            bb1[s][j] = v ? (b_ih1[j * H + u] + b_hh1[j * H + u]) : 0.0f;
            bb2[s][j] = v ? (b_ih2[j * H + u] + b_hh2[j * H + u]) : 0.0f;
            wxv[s][j] = v ? W_ih1[j * H + u] : 0.0f;
        }
    }

    float wl[16];                          // wave7: y-dot weights, rows q*16+i
    if (w == 7) {
#pragma unroll
        for (int i = 0; i < 16; ++i) {
            const int r = q * 16 + i;
            wl[i] = (r < H) ? W_lin[r] : 0.0f;
        }
    }
    const float blin = b_lin[0];

    float xcur = input[(size_t)(b0 + mcol) * TLEN + 0];

    __syncthreads();                       // zeros visible

    for (int k = 0; k <= TLEN; ++k) {
        const int rb   = (k + 1) & 1;      // holds h1(k-1), h2(k-2)
        const int wbuf = k & 1;
        const int kn   = (k + 1 < TLEN) ? (k + 1) : (TLEN - 1);
        const float xnext = input[(size_t)(b0 + mcol) * TLEN + kn];

        // ---- B-frags: 8x ds_read_b128, no perms ----
        bf16x8 B1h[2], B1l[2], B2h[2], B2l[2];
#pragma unroll
        for (int kt = 0; kt < 2; ++kt) {
            const int k0 = kt * 32 + q * 8;
            B1h[kt] = lds16(&hb[rb][0][mcol][k0]);
            B1l[kt] = lds16(&hb[rb][1][mcol][k0]);
            B2h[kt] = lds16(&hb[rb][2][mcol][k0]);
            B2l[kt] = lds16(&hb[rb][3][mcol][k0]);
        }

        // ---- wave7: deferred y(k-2) from h2 planes of [rb] ----
        if (w == 7 && k >= 2) {
            bf16x8 yh0 = lds16(&hb[rb][2][mcol][q * 16]);
            bf16x8 yh1 = lds16(&hb[rb][2][mcol][q * 16 + 8]);
            bf16x8 yl0 = lds16(&hb[rb][3][mcol][q * 16]);
            bf16x8 yl1 = lds16(&hb[rb][3][mcol][q * 16 + 8]);
            float yp = 0.0f;
#pragma unroll
            for (int i = 0; i < 8; ++i) {
                yp += wl[i]     * (bf_f(yh0[i]) + bf_f(yl0[i]));
                yp += wl[i + 8] * (bf_f(yh1[i]) + bf_f(yl1[i]));
            }
            yp += __shfl_xor(yp, 16);
            yp += __shfl_xor(yp, 32);
            if (q == 0) out[(size_t)(b0 + mcol) * TLEN + (k - 2)] = yp + blin;
        }

        // ---- per row-tile: mfma chains + lane-local acts ----
#pragma unroll
        for (int s = 0; s < 2; ++s) {
            const int t = tiles[s];
            if (t >= 13) continue;                     // dummy slot (uniform)
            const int u = 4 * t + q;

            f4 g1 = {0.0f, 0.0f, 0.0f, 0.0f};          // gates1(k)
            MFMA(g1, A1h[s][0], B1h[0]);  MFMA(g1, A1h[s][1], B1h[1]);
            MFMA(g1, A1h[s][0], B1l[0]);  MFMA(g1, A1h[s][1], B1l[1]);
            MFMA(g1, A1l[s][0], B1h[0]);  MFMA(g1, A1l[s][1], B1h[1]);

            f4 g2 = {0.0f, 0.0f, 0.0f, 0.0f};          // gates2(k-1)
            MFMA(g2, Aih[s][0], B1h[0]);  MFMA(g2, Aih[s][1], B1h[1]);
            MFMA(g2, Aih[s][0], B1l[0]);  MFMA(g2, Aih[s][1], B1l[1]);
            MFMA(g2, Ail[s][0], B1h[0]);  MFMA(g2, Ail[s][1], B1h[1]);
            MFMA(g2, Ahh[s][0], B2h[0]);  MFMA(g2, Ahh[s][1], B2h[1]);
            MFMA(g2, Ahh[s][0], B2l[0]);  MFMA(g2, Ahh[s][1], B2l[1]);
            MFMA(g2, Ahl[s][0], B2h[0]);  MFMA(g2, Ahl[s][1], B2h[1]);

            // L1 act (step k): acc reg j = gate j (i,f,g,o) of unit u
            const float i1 = sigm (g1[0] + bb1[s][0] + wxv[s][0] * xcur);
            const float f1 = sigm (g1[1] + bb1[s][1] + wxv[s][1] * xcur);
            const float gg = tanh_(g1[2] + bb1[s][2] + wxv[s][2] * xcur);
            const float o1 = sigm (g1[3] + bb1[s][3] + wxv[s][3] * xcur);
            c1[s] = f1 * c1[s] + i1 * gg;
            const float h1n = o1 * tanh_(c1[s]);
            if (u < H) {
                const short hh = bf_rne(h1n);          // same split as pack_hl
                hb[wbuf][0][mcol][u] = hh;
                hb[wbuf][1][mcol][u] = bf_rne(h1n - bf_f(hh));
            }

            // L2 act (step k-1; skipped at k=0 so h2(-1) stays 0)
            const float i2 = sigm (g2[0] + bb2[s][0]);
            const float f2 = sigm (g2[1] + bb2[s][1]);
            const float g2g= tanh_(g2[2] + bb2[s][2]);
            const float o2 = sigm (g2[3] + bb2[s][3]);
            if (k != 0) {
                c2[s] = f2 * c2[s] + i2 * g2g;
                const float h2n = o2 * tanh_(c2[s]);
                if (u < H) {
                    const short hh2 = bf_rne(h2n);
                    hb[wbuf][2][mcol][u] = hh2;
                    hb[wbuf][3][mcol][u] = bf_rne(h2n - bf_f(hh2));
                }
            }
        }

        __syncthreads();                                // the one barrier
        xcur = xnext;
    }

    // epilogue: y(T-1) from h2 planes of buffer (TLEN & 1) (= wbuf at k=TLEN)
    if (w == 7) {
        const int fb = TLEN & 1;
        bf16x8 yh0 = lds16(&hb[fb][2][mcol][q * 16]);
        bf16x8 yh1 = lds16(&hb[fb][2][mcol][q * 16 + 8]);
        bf16x8 yl0 = lds16(&hb[fb][3][mcol][q * 16]);
        bf16x8 yl1 = lds16(&hb[fb][3][mcol][q * 16 + 8]);
        float yp = 0.0f;
#pragma unroll
        for (int i = 0; i < 8; ++i) {
            yp += wl[i]     * (bf_f(yh0[i]) + bf_f(yl0[i]));
            yp += wl[i + 8] * (bf_f(yh1[i]) + bf_f(yl1[i]));
        }
        yp += __shfl_xor(yp, 16);
        yp += __shfl_xor(yp, 32);
        if (q == 0) out[(size_t)(b0 + mcol) * TLEN + (TLEN - 1)] = yp + blin;
    }
}

extern "C" void kernel_launch(void* const* d_in, const int* in_sizes, int n_in,
                              void* d_out, int out_size, void* d_ws, size_t ws_size,
                              hipStream_t stream)
{
    const float* input = (const float*)d_in[0];
    const float* W_ih1 = (const float*)d_in[1];
    const float* W_hh1 = (const float*)d_in[2];
    const float* b_ih1 = (const float*)d_in[3];
    const float* b_hh1 = (const float*)d_in[4];
    const float* W_ih2 = (const float*)d_in[5];
    const float* W_hh2 = (const float*)d_in[6];
    const float* b_ih2 = (const float*)d_in[7];
    const float* b_hh2 = (const float*)d_in[8];
    const float* W_lin = (const float*)d_in[9];
    const float* b_lin = (const float*)d_in[10];

    float* out = (float*)d_out;

    hipLaunchKernelGGL(lstm2_kernel, dim3(NBLK), dim3(NTHR), 0, stream,
                       input, W_ih1, W_hh1, b_ih1, b_hh1,
                       W_ih2, W_hh2, b_ih2, b_hh2, W_lin, b_lin,
                       out);
}

// Round 3
// 1244.043 us; speedup vs baseline: 1.5662x; 1.0807x over previous
//
#include <hip/hip_runtime.h>

// ---------------------------------------------------------------------------
// 2-layer LSTM (H=51) + Linear(51,1), B=1024, T=1024, fp32.
// R16b = R16 resubmit (previous round died on container acquisition, no data).
// R16 = R15 at 4 waves/SIMD: 14 waves x 1 tile each.
//   Post-mortem R15: derived counters are device-wide but only 64/256 CUs
//   active -> active-CU VALUBusy ~54%, MfmaUtil ~30%, occupancy 2 waves/SIMD.
//   Nearly VALU-issue-bound (260 transcendentals/step/CU) with ~46% latency
//   idle. VGPR=112 -> room for 4 waves/SIMD.
//   - 896 thr = 14 waves: wave w<13 owns tile w (one 16-row tile, 48 VGPR of
//     weights), wave 13 owns the deferred y-dot (decoupled from tile work),
//     waves_per_eu(4,4). 4-way TLP/SIMD hides each wave's serial chain.
//   - h planes PRE-SPLIT bf16 hi/lo, stride 88 (176B): B-frag = 8x
//     ds_read_b128, conflict-free permutation (R15-proven).
//   - gates = Whi.hhi + Whi.hlo + Wlo.hhi (3 mfma terms, R14-proven).
//   - W rows permuted prow=4u+g -> lane-local c/h update (R9+ proven).
//   - ONE barrier/step, L2 one step behind L1, ping-pong buffers, deferred
//     y(k-2) on wave 13, k==0 guard. Numerics identical to R15.
// ---------------------------------------------------------------------------

#define H     51
#define NROW  204      // 4*H
#define TLEN  1024
#define BPB   16       // batches per block (= mfma N)
#define NTHR  896      // 14 waves
#define NBLK  64
#define KPAD  88       // bf16 row stride (176B) -> conflict-free b128 reads

typedef __attribute__((ext_vector_type(8))) short bf16x8;   // 8 bf16 = 4 VGPRs
typedef __attribute__((ext_vector_type(4))) float f4;

__device__ __forceinline__ float frcp(float x) { return __builtin_amdgcn_rcpf(x); }
__device__ __forceinline__ float sigm(float x) { return frcp(1.0f + __expf(-x)); }
__device__ __forceinline__ float tanh_(float x) {
    return 1.0f - 2.0f * frcp(__expf(2.0f * x) + 1.0f);
}

__device__ __forceinline__ short bf_rne(float f) {        // fp32 -> bf16 RNE
    unsigned u = __float_as_uint(f);
    return (short)((u + 0x7FFFu + ((u >> 16) & 1u)) >> 16);
}
__device__ __forceinline__ float bf_f(short h) {          // bf16 -> fp32
    return __uint_as_float(((unsigned)(unsigned short)h) << 16);
}

__device__ __forceinline__ bf16x8 lds16(const short* p) { // one ds_read_b128
    return *(const bf16x8*)__builtin_assume_aligned(p, 16);
}

#define MFMA(ACC, A, B) \
    ACC = __builtin_amdgcn_mfma_f32_16x16x32_bf16((A), (B), (ACC), 0, 0, 0)

// A-frag for 16x16x32: lane holds A[m=lane&15][k=quad*8+j], j=0..7.
// Source W is [204][51] row-major, PyTorch rows g*51+u; permuted row
// prow = 4u+g -> src row = (prow&3)*51 + (prow>>2). Zero-pad prow>=204, k>=51.
__device__ __forceinline__ void load_wfrag(const float* __restrict__ W,
                                           int tile, int kt, int q, int mcol,
                                           bf16x8* hi, bf16x8* lo)
{
    bf16x8 h, l;
    const int prow = tile * 16 + mcol;
#pragma unroll
    for (int j = 0; j < 8; ++j) {
        const int kk = kt * 32 + q * 8 + j;
        float v = 0.0f;
        if (prow < NROW && kk < H) {
            const int srow = (prow & 3) * H + (prow >> 2);
            v = W[srow * H + kk];
        }
        const short hb = bf_rne(v);
        h[j] = hb;
        l[j] = bf_rne(v - bf_f(hb));
    }
    *hi = h;
    *lo = l;
}

__global__
__attribute__((amdgpu_flat_work_group_size(NTHR, NTHR), amdgpu_waves_per_eu(4, 4)))
void lstm2_kernel(const float* __restrict__ input,
                  const float* __restrict__ W_ih1, const float* __restrict__ W_hh1,
                  const float* __restrict__ b_ih1, const float* __restrict__ b_hh1,
                  const float* __restrict__ W_ih2, const float* __restrict__ W_hh2,
                  const float* __restrict__ b_ih2, const float* __restrict__ b_hh2,
                  const float* __restrict__ W_lin, const float* __restrict__ b_lin,
                  float* __restrict__ out)
{
    const int tid  = threadIdx.x;
    const int w    = tid >> 6;        // wave 0..13
    const int lane = tid & 63;
    const int q    = lane >> 4;       // quad
    const int mcol = lane & 15;       // batch column (and A-frag m)
    const int b0   = blockIdx.x * BPB;

    const bool tile_wave = (w < 13);
    const bool y_wave    = (w == 13);

    // [buf][plane][mcol][k]; planes: 0=h1hi 1=h1lo 2=h2hi 3=h2lo.
    // Rows k in [51,88) stay zero (init below, never written).
    __shared__ __align__(16) short hb[2][4][BPB][KPAD];

    {
        short* hz = &hb[0][0][0][0];
        for (int i = tid; i < 2 * 4 * BPB * KPAD; i += NTHR) hz[i] = 0;
    }

    // ---- persistent weight fragments: wave w owns tile w ------------------
    bf16x8 A1h[2], A1l[2];                // W_hh1 hi/lo  x Ktile
    bf16x8 Aih[2], Ail[2];                // W_ih2 hi/lo
    bf16x8 Ahh[2], Ahl[2];                // W_hh2 hi/lo
    f4 bb1, bb2, wxv;
    float c1 = 0.0f, c2 = 0.0f;
    const int t = w;                      // tile (>=13 -> unused)
    const int u = 4 * t + q;              // this lane's unit

    if (tile_wave) {
#pragma unroll
        for (int kt = 0; kt < 2; ++kt) {
            load_wfrag(W_hh1, t, kt, q, mcol, &A1h[kt], &A1l[kt]);
            load_wfrag(W_ih2, t, kt, q, mcol, &Aih[kt], &Ail[kt]);
            load_wfrag(W_hh2, t, kt, q, mcol, &Ahh[kt], &Ahl[kt]);
        }
#pragma unroll
        for (int j = 0; j < 4; ++j) {     // gate j of unit u (PyTorch row j*H+u)
            const bool v = (u < H);
            bb1[j] = v ? (b_ih1[j * H + u] + b_hh1[j * H + u]) : 0.0f;
            bb2[j] = v ? (b_ih2[j * H + u] + b_hh2[j * H + u]) : 0.0f;
            wxv[j] = v ? W_ih1[j * H + u] : 0.0f;
        }
    }

    float wl[16];                          // wave13: y-dot weights, rows q*16+i
    if (y_wave) {
#pragma unroll
        for (int i = 0; i < 16; ++i) {
            const int r = q * 16 + i;
            wl[i] = (r < H) ? W_lin[r] : 0.0f;
        }
    }
    const float blin = b_lin[0];

    float xcur = input[(size_t)(b0 + mcol) * TLEN + 0];

    __syncthreads();                       // zeros visible

    for (int k = 0; k <= TLEN; ++k) {
        const int rb   = (k + 1) & 1;      // holds h1(k-1), h2(k-2)
        const int wbuf = k & 1;
        const int kn   = (k + 1 < TLEN) ? (k + 1) : (TLEN - 1);
        const float xnext = input[(size_t)(b0 + mcol) * TLEN + kn];

        if (tile_wave) {
            // ---- B-frags: 8x ds_read_b128, no perms ----
            bf16x8 B1h[2], B1l[2], B2h[2], B2l[2];
#pragma unroll
            for (int kt = 0; kt < 2; ++kt) {
                const int k0 = kt * 32 + q * 8;
                B1h[kt] = lds16(&hb[rb][0][mcol][k0]);
                B1l[kt] = lds16(&hb[rb][1][mcol][k0]);
                B2h[kt] = lds16(&hb[rb][2][mcol][k0]);
                B2l[kt] = lds16(&hb[rb][3][mcol][k0]);
            }

            f4 g1 = {0.0f, 0.0f, 0.0f, 0.0f};          // gates1(k)
            MFMA(g1, A1h[0], B1h[0]);  MFMA(g1, A1h[1], B1h[1]);
            MFMA(g1, A1h[0], B1l[0]);  MFMA(g1, A1h[1], B1l[1]);
            MFMA(g1, A1l[0], B1h[0]);  MFMA(g1, A1l[1], B1h[1]);

            f4 g2 = {0.0f, 0.0f, 0.0f, 0.0f};          // gates2(k-1)
            MFMA(g2, Aih[0], B1h[0]);  MFMA(g2, Aih[1], B1h[1]);
            MFMA(g2, Aih[0], B1l[0]);  MFMA(g2, Aih[1], B1l[1]);
            MFMA(g2, Ail[0], B1h[0]);  MFMA(g2, Ail[1], B1h[1]);
            MFMA(g2, Ahh[0], B2h[0]);  MFMA(g2, Ahh[1], B2h[1]);
            MFMA(g2, Ahh[0], B2l[0]);  MFMA(g2, Ahh[1], B2l[1]);
            MFMA(g2, Ahl[0], B2h[0]);  MFMA(g2, Ahl[1], B2h[1]);

            // L1 act (step k): acc reg j = gate j (i,f,g,o) of unit u
            const float i1 = sigm (g1[0] + bb1[0] + wxv[0] * xcur);
            const float f1 = sigm (g1[1] + bb1[1] + wxv[1] * xcur);
            const float gg = tanh_(g1[2] + bb1[2] + wxv[2] * xcur);
            const float o1 = sigm (g1[3] + bb1[3] + wxv[3] * xcur);
            c1 = f1 * c1 + i1 * gg;
            const float h1n = o1 * tanh_(c1);
            if (u < H) {
                const short hh = bf_rne(h1n);          // same split as pack_hl
                hb[wbuf][0][mcol][u] = hh;
                hb[wbuf][1][mcol][u] = bf_rne(h1n - bf_f(hh));
            }

            // L2 act (step k-1; skipped at k=0 so h2(-1) stays 0)
            const float i2 = sigm (g2[0] + bb2[0]);
            const float f2 = sigm (g2[1] + bb2[1]);
            const float g2g= tanh_(g2[2] + bb2[2]);
            const float o2 = sigm (g2[3] + bb2[3]);
            if (k != 0) {
                c2 = f2 * c2 + i2 * g2g;
                const float h2n = o2 * tanh_(c2);
                if (u < H) {
                    const short hh2 = bf_rne(h2n);
                    hb[wbuf][2][mcol][u] = hh2;
                    hb[wbuf][3][mcol][u] = bf_rne(h2n - bf_f(hh2));
                }
            }
        } else if (y_wave && k >= 2) {
            // ---- deferred y(k-2) from h2 planes of [rb] (stable this iter) --
            bf16x8 yh0 = lds16(&hb[rb][2][mcol][q * 16]);
            bf16x8 yh1 = lds16(&hb[rb][2][mcol][q * 16 + 8]);
            bf16x8 yl0 = lds16(&hb[rb][3][mcol][q * 16]);
            bf16x8 yl1 = lds16(&hb[rb][3][mcol][q * 16 + 8]);
            float yp = 0.0f;
#pragma unroll
            for (int i = 0; i < 8; ++i) {
                yp += wl[i]     * (bf_f(yh0[i]) + bf_f(yl0[i]));
                yp += wl[i + 8] * (bf_f(yh1[i]) + bf_f(yl1[i]));
            }
            yp += __shfl_xor(yp, 16);
            yp += __shfl_xor(yp, 32);
            if (q == 0) out[(size_t)(b0 + mcol) * TLEN + (k - 2)] = yp + blin;
        }

        __syncthreads();                                // the one barrier
        xcur = xnext;
    }

    // epilogue: y(T-1) from h2 planes of buffer (TLEN & 1) (= wbuf at k=TLEN)
    if (y_wave) {
        const int fb = TLEN & 1;
        bf16x8 yh0 = lds16(&hb[fb][2][mcol][q * 16]);
        bf16x8 yh1 = lds16(&hb[fb][2][mcol][q * 16 + 8]);
        bf16x8 yl0 = lds16(&hb[fb][3][mcol][q * 16]);
        bf16x8 yl1 = lds16(&hb[fb][3][mcol][q * 16 + 8]);
        float yp = 0.0f;
#pragma unroll
        for (int i = 0; i < 8; ++i) {
            yp += wl[i]     * (bf_f(yh0[i]) + bf_f(yl0[i]));
            yp += wl[i + 8] * (bf_f(yh1[i]) + bf_f(yl1[i]));
        }
        yp += __shfl_xor(yp, 16);
        yp += __shfl_xor(yp, 32);
        if (q == 0) out[(size_t)(b0 + mcol) * TLEN + (TLEN - 1)] = yp + blin;
    }
}

extern "C" void kernel_launch(void* const* d_in, const int* in_sizes, int n_in,
                              void* d_out, int out_size, void* d_ws, size_t ws_size,
                              hipStream_t stream)
{
    const float* input = (const float*)d_in[0];
    const float* W_ih1 = (const float*)d_in[1];
    const float* W_hh1 = (const float*)d_in[2];
    const float* b_ih1 = (const float*)d_in[3];
    const float* b_hh1 = (const float*)d_in[4];
    const float* W_ih2 = (const float*)d_in[5];
    const float* W_hh2 = (const float*)d_in[6];
    const float* b_ih2 = (const float*)d_in[7];
    const float* b_hh2 = (const float*)d_in[8];
    const float* W_lin = (const float*)d_in[9];
    const float* b_lin = (const float*)d_in[10];

    float* out = (float*)d_out;

    hipLaunchKernelGGL(lstm2_kernel, dim3(NBLK), dim3(NTHR), 0, stream,
                       input, W_ih1, W_hh1, b_ih1, b_hh1,
                       W_ih2, W_hh2, b_ih2, b_hh2, W_lin, b_lin,
                       out);
}

// Round 4
// 771.635 us; speedup vs baseline: 2.5250x; 1.6122x over previous
//
#include <hip/hip_runtime.h>

// ---------------------------------------------------------------------------
// 2-layer LSTM (H=51) + Linear(51,1), B=1024, T=1024, fp32.
// R17 = R16 with fp16 single-term MFMA (replaces bf16 hi/lo 3-term).
//   Post-mortem R16: occupancy exhausted (14 waves/CU, 3.5/SIMD); step time
//   = per-CU issue serialization: VALU ~1716 cy/SIMD/step, DS ~1600 cy/step.
//   Only lever left: cut per-step WORK.
//   - h and W in fp16 (10-bit mantissa, 2^-11 rel err = 8x better than bf16;
//     RNE, unbiased). R13's bf16-single failure (1.95e-3) scaled by 1/8 ->
//     ~2.5e-4 expected absmax. Single mfma term per operand pair:
//     MFMA 18 -> 6, DS reads 8 -> 4 b128, writes 4 -> 2 b16 per wave-step.
//   - bias+Wx folded into MFMA acc init (g1 init = bb1 + wxv*x, g2 = bb2):
//     saves 8 v_add per wave-step.
//   - exp2-domain gates: W rows/biases pre-scaled by log2e (2*log2e for the
//     tanh gate g) -> v_exp_f32 used directly without per-exp 1/ln2 mul
//     (saves 8 muls/wave-step). c-tanh needs 1 runtime mul (c is linear).
//   - k-loop unrolled x2: rb/wbuf compile-time -> LDS addresses hoisted.
//   - Skeleton unchanged (R9-R16-proven): 14 waves (13 tile + 1 y),
//     waves_per_eu(4,4), prow=4u+g lane-local acts, plane stride 88 (176B)
//     conflict-free b128 reads, ONE barrier/step, L2 one step behind L1,
//     ping-pong buffers, deferred y(k-2) on wave 13, k==0 guard.
// ---------------------------------------------------------------------------

#define H     51
#define NROW  204      // 4*H
#define TLEN  1024
#define BPB   16       // batches per block (= mfma N)
#define NTHR  896      // 14 waves
#define NBLK  64
#define KPAD  88       // fp16 row stride (176B) -> conflict-free b128 reads

#define LOG2E  1.442695041f
#define LOG2E2 2.885390082f

typedef __attribute__((ext_vector_type(8))) _Float16 half8;  // 8 f16 = 4 VGPRs
typedef __attribute__((ext_vector_type(4))) float f4;

__device__ __forceinline__ float frcp(float x) { return __builtin_amdgcn_rcpf(x); }
#if __has_builtin(__builtin_amdgcn_exp2f)
__device__ __forceinline__ float ex2(float x) { return __builtin_amdgcn_exp2f(x); }
#else
__device__ __forceinline__ float ex2(float x) { return __expf(x * 0.6931471806f); }
#endif

__device__ __forceinline__ half8 lds8h(const _Float16* p) {  // one ds_read_b128
    return *(const half8*)__builtin_assume_aligned(p, 16);
}

#define MFMA(ACC, A, B) \
    ACC = __builtin_amdgcn_mfma_f32_16x16x32_f16((A), (B), (ACC), 0, 0, 0)

// A-frag for 16x16x32: lane holds A[m=lane&15][k=quad*8+j], j=0..7.
// Source W is [204][51] row-major, PyTorch rows g*51+u; permuted row
// prow = 4u+g -> src row = (prow&3)*51 + (prow>>2). Zero-pad prow>=204, k>=51.
// Rows pre-scaled by log2e (2*log2e for tanh gate g==2) for exp2-domain acts.
__device__ __forceinline__ half8 load_wfrag(const float* __restrict__ W,
                                            int tile, int kt, int q, int mcol)
{
    half8 hf;
    const int prow = tile * 16 + mcol;
    const float sc = ((prow & 3) == 2) ? LOG2E2 : LOG2E;
#pragma unroll
    for (int j = 0; j < 8; ++j) {
        const int kk = kt * 32 + q * 8 + j;
        float v = 0.0f;
        if (prow < NROW && kk < H) {
            const int srow = (prow & 3) * H + (prow >> 2);
            v = W[srow * H + kk];
        }
        hf[j] = (_Float16)(v * sc);
    }
    return hf;
}

__global__
__attribute__((amdgpu_flat_work_group_size(NTHR, NTHR), amdgpu_waves_per_eu(4, 4)))
void lstm2_kernel(const float* __restrict__ input,
                  const float* __restrict__ W_ih1, const float* __restrict__ W_hh1,
                  const float* __restrict__ b_ih1, const float* __restrict__ b_hh1,
                  const float* __restrict__ W_ih2, const float* __restrict__ W_hh2,
                  const float* __restrict__ b_ih2, const float* __restrict__ b_hh2,
                  const float* __restrict__ W_lin, const float* __restrict__ b_lin,
                  float* __restrict__ out)
{
    const int tid  = threadIdx.x;
    const int w    = tid >> 6;        // wave 0..13
    const int lane = tid & 63;
    const int q    = lane >> 4;       // quad
    const int mcol = lane & 15;       // batch column (and A-frag m)
    const int b0   = blockIdx.x * BPB;

    const bool tile_wave = (w < 13);
    const bool y_wave    = (w == 13);

    // [buf][plane][mcol][k]; planes: 0=h1 1=h2 (fp16).
    // Rows k in [51,88) stay zero (init below, never written).
    __shared__ __align__(16) _Float16 hb[2][2][BPB][KPAD];

    {
        _Float16* hz = &hb[0][0][0][0];
        for (int i = tid; i < 2 * 2 * BPB * KPAD; i += NTHR) hz[i] = (_Float16)0.0f;
    }

    // ---- persistent weight fragments: wave w owns tile w ------------------
    half8 A1[2], Ai[2], Ah[2];            // W_hh1 / W_ih2 / W_hh2, x Ktile
    f4 bb1, bb2, wxv;
    float c1 = 0.0f, c2 = 0.0f;
    const int t = w;                      // tile
    const int u = 4 * t + q;              // this lane's unit

    if (tile_wave) {
#pragma unroll
        for (int kt = 0; kt < 2; ++kt) {
            A1[kt] = load_wfrag(W_hh1, t, kt, q, mcol);
            Ai[kt] = load_wfrag(W_ih2, t, kt, q, mcol);
            Ah[kt] = load_wfrag(W_hh2, t, kt, q, mcol);
        }
#pragma unroll
        for (int j = 0; j < 4; ++j) {     // gate j of unit u (PyTorch row j*H+u)
            const bool v = (u < H);
            const float sc = (j == 2) ? LOG2E2 : LOG2E;
            bb1[j] = v ? sc * (b_ih1[j * H + u] + b_hh1[j * H + u]) : 0.0f;
            bb2[j] = v ? sc * (b_ih2[j * H + u] + b_hh2[j * H + u]) : 0.0f;
            wxv[j] = v ? sc * W_ih1[j * H + u] : 0.0f;
        }
    }

    float wl[16];                          // wave13: y-dot weights, rows q*16+i
    if (y_wave) {
#pragma unroll
        for (int i = 0; i < 16; ++i) {
            const int r = q * 16 + i;
            wl[i] = (r < H) ? W_lin[r] : 0.0f;
        }
    }
    const float blin = b_lin[0];

    float xcur = input[(size_t)(b0 + mcol) * TLEN + 0];

    __syncthreads();                       // zeros visible

// One LSTM step: reads buf RB (h1(k-1), h2(k-2)), writes buf WB.
// RB/WB are literals -> LDS addresses loop-invariant (unroll x2 below).
#define STEP(KK, RB, WB)                                                       \
do {                                                                           \
    const int k_  = (KK);                                                      \
    const int kn_ = (k_ + 1 < TLEN) ? (k_ + 1) : (TLEN - 1);                   \
    const float xnext_ = input[(size_t)(b0 + mcol) * TLEN + kn_];              \
    if (tile_wave) {                                                           \
        half8 B1a = lds8h(&hb[RB][0][mcol][q * 8]);                            \
        half8 B1b = lds8h(&hb[RB][0][mcol][32 + q * 8]);                       \
        half8 B2a = lds8h(&hb[RB][1][mcol][q * 8]);                            \
        half8 B2b = lds8h(&hb[RB][1][mcol][32 + q * 8]);                       \
        f4 g1, g2;                                                             \
        g1[0] = fmaf(wxv[0], xcur, bb1[0]);                                    \
        g1[1] = fmaf(wxv[1], xcur, bb1[1]);                                    \
        g1[2] = fmaf(wxv[2], xcur, bb1[2]);                                    \
        g1[3] = fmaf(wxv[3], xcur, bb1[3]);                                    \
        g2 = bb2;                                                              \
        MFMA(g1, A1[0], B1a);  MFMA(g1, A1[1], B1b);                           \
        MFMA(g2, Ai[0], B1a);  MFMA(g2, Ai[1], B1b);                           \
        MFMA(g2, Ah[0], B2a);  MFMA(g2, Ah[1], B2b);                           \
        /* L1 acts (step k); gates already in exp2 domain */                   \
        const float i1 = frcp(1.0f + ex2(-g1[0]));                             \
        const float f1 = frcp(1.0f + ex2(-g1[1]));                             \
        const float gg = 1.0f - 2.0f * frcp(ex2(g1[2]) + 1.0f);                \
        const float o1 = frcp(1.0f + ex2(-g1[3]));                             \
        c1 = f1 * c1 + i1 * gg;                                                \
        const float h1n = o1 * (1.0f - 2.0f * frcp(ex2(c1 * LOG2E2) + 1.0f));  \
        if (u < H) hb[WB][0][mcol][u] = (_Float16)h1n;                         \
        /* L2 acts (step k-1; skipped at k=0 so h2(-1) stays 0) */             \
        const float i2 = frcp(1.0f + ex2(-g2[0]));                             \
        const float f2 = frcp(1.0f + ex2(-g2[1]));                             \
        const float gh = 1.0f - 2.0f * frcp(ex2(g2[2]) + 1.0f);                \
        const float o2 = frcp(1.0f + ex2(-g2[3]));                             \
        if (k_ != 0) {                                                         \
            c2 = f2 * c2 + i2 * gh;                                            \
            const float h2n = o2 * (1.0f - 2.0f * frcp(ex2(c2 * LOG2E2) + 1.0f)); \
            if (u < H) hb[WB][1][mcol][u] = (_Float16)h2n;                     \
        }                                                                      \
    } else if (y_wave && k_ >= 2) {                                            \
        /* deferred y(k-2) from h2 plane of buf RB (stable this iter) */       \
        half8 y0 = lds8h(&hb[RB][1][mcol][q * 16]);                            \
        half8 y1 = lds8h(&hb[RB][1][mcol][q * 16 + 8]);                        \
        float yp = 0.0f;                                                       \
        _Pragma("unroll")                                                      \
        for (int i = 0; i < 8; ++i) {                                          \
            yp += wl[i]     * (float)y0[i];                                    \
            yp += wl[i + 8] * (float)y1[i];                                    \
        }                                                                      \
        yp += __shfl_xor(yp, 16);                                              \
        yp += __shfl_xor(yp, 32);                                              \
        if (q == 0) out[(size_t)(b0 + mcol) * TLEN + (k_ - 2)] = yp + blin;    \
    }                                                                          \
    __syncthreads();                                                           \
    xcur = xnext_;                                                             \
} while (0)

    // k even: rb=1, wbuf=0; k odd: rb=0, wbuf=1.  TLEN even -> tail is even.
    for (int k = 0; k < TLEN; k += 2) {
        STEP(k, 1, 0);
        STEP(k + 1, 0, 1);
    }
    STEP(TLEN, 1, 0);
#undef STEP

    // epilogue: y(T-1) from h2 plane of buf (TLEN & 1) = 0 (= wbuf at k=TLEN)
    if (y_wave) {
        half8 y0 = lds8h(&hb[0][1][mcol][q * 16]);
        half8 y1 = lds8h(&hb[0][1][mcol][q * 16 + 8]);
        float yp = 0.0f;
#pragma unroll
        for (int i = 0; i < 8; ++i) {
            yp += wl[i]     * (float)y0[i];
            yp += wl[i + 8] * (float)y1[i];
        }
        yp += __shfl_xor(yp, 16);
        yp += __shfl_xor(yp, 32);
        if (q == 0) out[(size_t)(b0 + mcol) * TLEN + (TLEN - 1)] = yp + blin;
    }
}

extern "C" void kernel_launch(void* const* d_in, const int* in_sizes, int n_in,
                              void* d_out, int out_size, void* d_ws, size_t ws_size,
                              hipStream_t stream)
{
    const float* input = (const float*)d_in[0];
    const float* W_ih1 = (const float*)d_in[1];
    const float* W_hh1 = (const float*)d_in[2];
    const float* b_ih1 = (const float*)d_in[3];
    const float* b_hh1 = (const float*)d_in[4];
    const float* W_ih2 = (const float*)d_in[5];
    const float* W_hh2 = (const float*)d_in[6];
    const float* b_ih2 = (const float*)d_in[7];
    const float* b_hh2 = (const float*)d_in[8];
    const float* W_lin = (const float*)d_in[9];
    const float* b_lin = (const float*)d_in[10];

    float* out = (float*)d_out;

    hipLaunchKernelGGL(lstm2_kernel, dim3(NBLK), dim3(NTHR), 0, stream,
                       input, W_ih1, W_hh1, b_ih1, b_hh1,
                       W_ih2, W_hh2, b_ih2, b_hh2, W_lin, b_lin,
                       out);
}